// Round 1
// baseline (1228.442 us; speedup 1.0000x reference)
//
#include <hip/hip_runtime.h>

#define B_SZ 4
#define T_SZ 2048
#define C_SZ 2048
#define H_SZ 16
#define D_SZ 128

typedef __attribute__((ext_vector_type(8))) __bf16 bf16x8;
typedef __attribute__((ext_vector_type(4))) float f32x4;
typedef __attribute__((ext_vector_type(4))) unsigned short us4;

static __device__ __forceinline__ unsigned short f2bf(float f) {
  unsigned u = __builtin_bit_cast(unsigned, f);
  u += 0x7fffu + ((u >> 16) & 1u);
  return (unsigned short)(u >> 16);
}

static __device__ __forceinline__ void gload16(const void* g, void* l) {
  __builtin_amdgcn_global_load_lds((__attribute__((address_space(1))) void*)(g),
                                   (__attribute__((address_space(3))) void*)(l), 16, 0, 0);
}

__global__ __launch_bounds__(256) void cast_f32_bf16(const float* __restrict__ src,
                                                     unsigned short* __restrict__ dst, int n4) {
  int i = blockIdx.x * 256 + threadIdx.x;
  if (i >= n4) return;
  float4 v = ((const float4*)src)[i];
  us4 o;
  o[0] = f2bf(v.x); o[1] = f2bf(v.y); o[2] = f2bf(v.z); o[3] = f2bf(v.w);
  ((us4*)dst)[i] = o;
}

// C[m,n] = sum_k A[m,k]*W[n,k].  A: MxK bf16 row-major, W: NxK bf16 row-major.
// EPI 1: RoPE epilogue -> bf16 (uses cosp/sinp; outScale folds 1/sqrt(d) for Q)
// EPI 2: transposed store -> Vt[((b*H+h)*D + d)*T + t] bf16
// EPI 3: plain fp32 store
template <int EPI>
__global__ __launch_bounds__(256) void gemm_bt(const unsigned short* __restrict__ A,
                                               const unsigned short* __restrict__ W,
                                               void* __restrict__ out,
                                               const float* __restrict__ cosp,
                                               const float* __restrict__ sinp,
                                               float outScale, int M, int N, int K) {
  __shared__ unsigned short As[128 * 32];
  __shared__ unsigned short Bs[128 * 32];
  const int tid = threadIdx.x;
  const int wave = tid >> 6, lane = tid & 63, quad = lane >> 4, l15 = lane & 15;
  const int m0 = blockIdx.y * 128, n0 = blockIdx.x * 128;
  f32x4 acc[2][8] = {};
  for (int kt = 0; kt < K; kt += 32) {
    __syncthreads();
#pragma unroll
    for (int s = 0; s < 2; ++s) {
      int i = s * 256 + tid;
      gload16(A + (size_t)(m0 + (i >> 2)) * K + kt + (i & 3) * 8, (char*)As + i * 16);
      gload16(W + (size_t)(n0 + (i >> 2)) * K + kt + (i & 3) * 8, (char*)Bs + i * 16);
    }
    __syncthreads();
    bf16x8 a0 = *(const bf16x8*)&As[(wave * 32 + l15) * 32 + quad * 8];
    bf16x8 a1 = *(const bf16x8*)&As[(wave * 32 + 16 + l15) * 32 + quad * 8];
#pragma unroll
    for (int nt = 0; nt < 8; ++nt) {
      bf16x8 b = *(const bf16x8*)&Bs[(nt * 16 + l15) * 32 + quad * 8];
      acc[0][nt] = __builtin_amdgcn_mfma_f32_16x16x32_bf16(a0, b, acc[0][nt], 0, 0, 0);
      acc[1][nt] = __builtin_amdgcn_mfma_f32_16x16x32_bf16(a1, b, acc[1][nt], 0, 0, 0);
    }
  }
  const int mb = m0 + wave * 32;
  if (EPI == 1) {
    unsigned short* O = (unsigned short*)out;
#pragma unroll
    for (int mt = 0; mt < 2; ++mt)
#pragma unroll
      for (int r = 0; r < 4; ++r) {
        int m = mb + mt * 16 + quad * 4 + r;
        int t = m & (T_SZ - 1);
#pragma unroll
        for (int nt = 0; nt < 4; ++nt) {
          int dd = nt * 16 + l15;
          float c = cosp[t * 64 + dd];
          float s = sinp[t * 64 + dd];
          float x1 = acc[mt][nt][r], x2 = acc[mt][nt + 4][r];
          O[(size_t)m * N + n0 + dd]      = f2bf((x1 * c + x2 * s) * outScale);
          O[(size_t)m * N + n0 + dd + 64] = f2bf((x1 * c - x2 * s) * outScale);
        }
      }
  } else if (EPI == 2) {
    unsigned short* O = (unsigned short*)out;
#pragma unroll
    for (int mt = 0; mt < 2; ++mt) {
      int m4 = mb + mt * 16 + quad * 4;  // 4 consecutive rows (same b)
      int bb = m4 >> 11;
      int t = m4 & (T_SZ - 1);
#pragma unroll
      for (int nt = 0; nt < 8; ++nt) {
        int n = n0 + nt * 16 + l15;
        int h = n >> 7, d = n & (D_SZ - 1);
        us4 pk;
        pk[0] = f2bf(acc[mt][nt][0]);
        pk[1] = f2bf(acc[mt][nt][1]);
        pk[2] = f2bf(acc[mt][nt][2]);
        pk[3] = f2bf(acc[mt][nt][3]);
        *(us4*)&O[((size_t)((bb * H_SZ + h) * D_SZ + d)) * T_SZ + t] = pk;
      }
    }
  } else {
    float* O = (float*)out;
#pragma unroll
    for (int mt = 0; mt < 2; ++mt)
#pragma unroll
      for (int nt = 0; nt < 8; ++nt)
#pragma unroll
        for (int r = 0; r < 4; ++r) {
          int m = mb + mt * 16 + quad * 4 + r;
          O[(size_t)m * N + n0 + nt * 16 + l15] = acc[mt][nt][r];
        }
  }
}

// Flash attention: Q,K are [B*T][C] bf16 (rope applied, Q pre-scaled by 1/sqrt(d)),
// Vt is [(b*H+h)*D + d][T] bf16.  Y out: [B*T][C] bf16.
// Block: 64 q-rows of one (b,h); 4 waves x 16 rows; kv-tiles of 64.
__global__ __launch_bounds__(256) void attn_fused(const unsigned short* __restrict__ Q,
                                                  const unsigned short* __restrict__ Kg,
                                                  const unsigned short* __restrict__ Vt,
                                                  unsigned short* __restrict__ Y) {
  __shared__ unsigned short Qs[64 * 128];
  __shared__ unsigned short Ks[64 * 128];
  __shared__ unsigned short Vs[128 * 64];   // [d][kv]
  __shared__ unsigned short Ps[4][16 * 64]; // per-wave P round-trip
  const int tid = threadIdx.x;
  const int wave = tid >> 6, lane = tid & 63, quad = lane >> 4, l15 = lane & 15;
  const int qt = blockIdx.x, bh = blockIdx.y;
  const int b = bh >> 4, h = bh & 15;
  const float LOG2E = 1.44269504088896f;

  size_t qbase = ((size_t)(b * T_SZ + qt * 64)) * C_SZ + h * D_SZ;
#pragma unroll
  for (int s = 0; s < 4; ++s) {
    int i = s * 256 + tid;
    gload16(Q + qbase + (size_t)(i >> 4) * C_SZ + (i & 15) * 8, (char*)Qs + i * 16);
  }
  float mstate[4], lstate[4];
#pragma unroll
  for (int r = 0; r < 4; ++r) { mstate[r] = -1e30f; lstate[r] = 0.f; }
  f32x4 o[8] = {};

  for (int kt = 0; kt < T_SZ / 64; ++kt) {
    __syncthreads();  // prev iter done with Ks/Vs (and Qs load covered on iter 0)
    size_t kbase = ((size_t)(b * T_SZ + kt * 64)) * C_SZ + h * D_SZ;
    size_t vbase = ((size_t)(bh * D_SZ)) * T_SZ + kt * 64;
#pragma unroll
    for (int s = 0; s < 4; ++s) {
      int i = s * 256 + tid;
      gload16(Kg + kbase + (size_t)(i >> 4) * C_SZ + (i & 15) * 8, (char*)Ks + i * 16);
      gload16(Vt + vbase + (size_t)(i >> 3) * T_SZ + (i & 7) * 8, (char*)Vs + i * 16);
    }
    __syncthreads();
    // S = Q K^T  (16 q-rows x 64 kv per wave)
    bf16x8 aq[4];
#pragma unroll
    for (int ks = 0; ks < 4; ++ks)
      aq[ks] = *(const bf16x8*)&Qs[(wave * 16 + l15) * D_SZ + ks * 32 + quad * 8];
    f32x4 sf[4] = {};
#pragma unroll
    for (int nt = 0; nt < 4; ++nt)
#pragma unroll
      for (int ks = 0; ks < 4; ++ks) {
        bf16x8 bk = *(const bf16x8*)&Ks[(nt * 16 + l15) * D_SZ + ks * 32 + quad * 8];
        sf[nt] = __builtin_amdgcn_mfma_f32_16x16x32_bf16(aq[ks], bk, sf[nt], 0, 0, 0);
      }
    // online softmax (rows quad*4+r; reduce across the 16 lanes of the quad-group)
    float rmax[4];
#pragma unroll
    for (int r = 0; r < 4; ++r)
      rmax[r] = fmaxf(fmaxf(sf[0][r], sf[1][r]), fmaxf(sf[2][r], sf[3][r]));
#pragma unroll
    for (int off = 8; off >= 1; off >>= 1)
#pragma unroll
      for (int r = 0; r < 4; ++r) rmax[r] = fmaxf(rmax[r], __shfl_xor(rmax[r], off));
    float alpha[4], mnew[4], rsum[4];
#pragma unroll
    for (int r = 0; r < 4; ++r) {
      mnew[r] = fmaxf(mstate[r], rmax[r]);
      alpha[r] = exp2f((mstate[r] - mnew[r]) * LOG2E);
      rsum[r] = 0.f;
    }
#pragma unroll
    for (int nt = 0; nt < 4; ++nt)
#pragma unroll
      for (int r = 0; r < 4; ++r) {
        float p = exp2f((sf[nt][r] - mnew[r]) * LOG2E);
        rsum[r] += p;
        Ps[wave][(quad * 4 + r) * 64 + nt * 16 + l15] = f2bf(p);
      }
#pragma unroll
    for (int off = 8; off >= 1; off >>= 1)
#pragma unroll
      for (int r = 0; r < 4; ++r) rsum[r] += __shfl_xor(rsum[r], off);
#pragma unroll
    for (int r = 0; r < 4; ++r) {
      lstate[r] = lstate[r] * alpha[r] + rsum[r];
      mstate[r] = mnew[r];
    }
#pragma unroll
    for (int nt = 0; nt < 8; ++nt)
#pragma unroll
      for (int r = 0; r < 4; ++r) o[nt][r] *= alpha[r];
    __syncthreads();  // make Ps visible (cross-lane) before A-frag reads
    // O += P V   (P: 16x64 A-layout from LDS; V: B-frags from Vs[d][kv])
    bf16x8 ap[2];
#pragma unroll
    for (int ks = 0; ks < 2; ++ks)
      ap[ks] = *(const bf16x8*)&Ps[wave][l15 * 64 + ks * 32 + quad * 8];
#pragma unroll
    for (int nt = 0; nt < 8; ++nt)
#pragma unroll
      for (int ks = 0; ks < 2; ++ks) {
        bf16x8 bv = *(const bf16x8*)&Vs[(nt * 16 + l15) * 64 + ks * 32 + quad * 8];
        o[nt] = __builtin_amdgcn_mfma_f32_16x16x32_bf16(ap[ks], bv, o[nt], 0, 0, 0);
      }
  }
#pragma unroll
  for (int nt = 0; nt < 8; ++nt)
#pragma unroll
    for (int r = 0; r < 4; ++r) {
      int m = b * T_SZ + qt * 64 + wave * 16 + quad * 4 + r;
      int col = h * D_SZ + nt * 16 + l15;
      Y[(size_t)m * C_SZ + col] = f2bf(o[nt][r] / lstate[r]);
    }
}

extern "C" void kernel_launch(void* const* d_in, const int* in_sizes, int n_in,
                              void* d_out, int out_size, void* d_ws, size_t ws_size,
                              hipStream_t stream) {
  (void)in_sizes; (void)n_in; (void)out_size; (void)ws_size;
  const float* x    = (const float*)d_in[0];
  const float* cosp = (const float*)d_in[1];
  const float* sinp = (const float*)d_in[2];
  const float* wq   = (const float*)d_in[3];
  const float* wk   = (const float*)d_in[4];
  const float* wv   = (const float*)d_in[5];
  const float* wo   = (const float*)d_in[6];
  float* out = (float*)d_out;

  const size_t XE = (size_t)B_SZ * T_SZ * C_SZ;  // 16,777,216 elements
  const size_t WE = (size_t)C_SZ * C_SZ;         // 4,194,304 elements
  unsigned short* Xb = (unsigned short*)d_ws;    // bf16 x          (33.5 MB)
  unsigned short* Qb = Xb + XE;                  // roped+scaled Q  (33.5 MB)
  unsigned short* Kb = Qb + XE;                  // roped K         (33.5 MB)
  unsigned short* Vt = Kb + XE;                  // V transposed    (33.5 MB)
  unsigned short* Wb = Vt + XE;                  // weight slot     ( 8.4 MB)
  unsigned short* Y  = Xb;                       // alias: Xb dead after V GEMM

  const int M = B_SZ * T_SZ, N = C_SZ, K = C_SZ;
  dim3 ggrid(N / 128, M / 128);
  int nbx = (int)(XE / 4 / 256);
  int nbw = (int)(WE / 4 / 256);
  const float qscale = 0.088388347648318447f;  // 1/sqrt(128)

  cast_f32_bf16<<<nbx, 256, 0, stream>>>(x, Xb, (int)(XE / 4));

  cast_f32_bf16<<<nbw, 256, 0, stream>>>(wq, Wb, (int)(WE / 4));
  gemm_bt<1><<<ggrid, 256, 0, stream>>>(Xb, Wb, Qb, cosp, sinp, qscale, M, N, K);

  cast_f32_bf16<<<nbw, 256, 0, stream>>>(wk, Wb, (int)(WE / 4));
  gemm_bt<1><<<ggrid, 256, 0, stream>>>(Xb, Wb, Kb, cosp, sinp, 1.0f, M, N, K);

  cast_f32_bf16<<<nbw, 256, 0, stream>>>(wv, Wb, (int)(WE / 4));
  gemm_bt<2><<<ggrid, 256, 0, stream>>>(Xb, Wb, Vt, nullptr, nullptr, 1.0f, M, N, K);

  attn_fused<<<dim3(T_SZ / 64, B_SZ * H_SZ), 256, 0, stream>>>(Qb, Kb, Vt, Y);

  cast_f32_bf16<<<nbw, 256, 0, stream>>>(wo, Wb, (int)(WE / 4));
  gemm_bt<3><<<ggrid, 256, 0, stream>>>(Y, Wb, out, nullptr, nullptr, 1.0f, M, N, K);
}

// Round 2
// 1144.005 us; speedup vs baseline: 1.0738x; 1.0738x over previous
//
#include <hip/hip_runtime.h>

#define B_SZ 4
#define T_SZ 2048
#define C_SZ 2048
#define H_SZ 16
#define D_SZ 128

typedef __attribute__((ext_vector_type(8))) __bf16 bf16x8;
typedef __attribute__((ext_vector_type(4))) float f32x4;
typedef __attribute__((ext_vector_type(4))) unsigned short us4;

static __device__ __forceinline__ unsigned short f2bf(float f) {
  unsigned u = __builtin_bit_cast(unsigned, f);
  u += 0x7fffu + ((u >> 16) & 1u);
  return (unsigned short)(u >> 16);
}

static __device__ __forceinline__ void gload16(const void* g, void* l) {
  __builtin_amdgcn_global_load_lds((__attribute__((address_space(1))) void*)(g),
                                   (__attribute__((address_space(3))) void*)(l), 16, 0, 0);
}

__global__ __launch_bounds__(256) void cast_f32_bf16(const float* __restrict__ src,
                                                     unsigned short* __restrict__ dst, int n4) {
  int i = blockIdx.x * 256 + threadIdx.x;
  if (i >= n4) return;
  float4 v = ((const float4*)src)[i];
  us4 o;
  o[0] = f2bf(v.x); o[1] = f2bf(v.y); o[2] = f2bf(v.z); o[3] = f2bf(v.w);
  ((us4*)dst)[i] = o;
}

// C[m,n] = sum_k A[m,k]*W[n,k].  A: MxK bf16 row-major, W: NxK bf16 row-major.
// LDS tiles XOR-swizzled at 16B-chunk granularity (4 chunks/row of 64B):
// chunk c of row r stored at pos c^(r&3)  -> fragment reads go 8-way -> 4-way conflicts.
// EPI 1: RoPE epilogue -> bf16; EPI 2: transposed store -> Vt; EPI 3: fp32 store
template <int EPI>
__global__ __launch_bounds__(256) void gemm_bt(const unsigned short* __restrict__ A,
                                               const unsigned short* __restrict__ W,
                                               void* __restrict__ out,
                                               const float* __restrict__ cosp,
                                               const float* __restrict__ sinp,
                                               float outScale, int M, int N, int K) {
  __shared__ unsigned short As[128 * 32];
  __shared__ unsigned short Bs[128 * 32];
  const int tid = threadIdx.x;
  const int wave = tid >> 6, lane = tid & 63, quad = lane >> 4, l15 = lane & 15;
  const int m0 = blockIdx.y * 128, n0 = blockIdx.x * 128;
  f32x4 acc[2][8] = {};
  for (int kt = 0; kt < K; kt += 32) {
    __syncthreads();
#pragma unroll
    for (int s = 0; s < 2; ++s) {
      int i = s * 256 + tid;
      int row = i >> 2, pos = i & 3, c = pos ^ (row & 3);
      gload16(A + (size_t)(m0 + row) * K + kt + c * 8, (char*)As + i * 16);
      gload16(W + (size_t)(n0 + row) * K + kt + c * 8, (char*)Bs + i * 16);
    }
    __syncthreads();
    const int sw = (quad ^ (l15 & 3)) * 8;
    bf16x8 a0 = *(const bf16x8*)&As[(wave * 32 + l15) * 32 + sw];
    bf16x8 a1 = *(const bf16x8*)&As[(wave * 32 + 16 + l15) * 32 + sw];
#pragma unroll
    for (int nt = 0; nt < 8; ++nt) {
      bf16x8 b = *(const bf16x8*)&Bs[(nt * 16 + l15) * 32 + sw];
      acc[0][nt] = __builtin_amdgcn_mfma_f32_16x16x32_bf16(a0, b, acc[0][nt], 0, 0, 0);
      acc[1][nt] = __builtin_amdgcn_mfma_f32_16x16x32_bf16(a1, b, acc[1][nt], 0, 0, 0);
    }
  }
  const int mb = m0 + wave * 32;
  if (EPI == 1) {
    unsigned short* O = (unsigned short*)out;
#pragma unroll
    for (int mt = 0; mt < 2; ++mt)
#pragma unroll
      for (int r = 0; r < 4; ++r) {
        int m = mb + mt * 16 + quad * 4 + r;
        int t = m & (T_SZ - 1);
#pragma unroll
        for (int nt = 0; nt < 4; ++nt) {
          int dd = nt * 16 + l15;
          float c = cosp[t * 64 + dd];
          float s = sinp[t * 64 + dd];
          float x1 = acc[mt][nt][r], x2 = acc[mt][nt + 4][r];
          O[(size_t)m * N + n0 + dd]      = f2bf((x1 * c + x2 * s) * outScale);
          O[(size_t)m * N + n0 + dd + 64] = f2bf((x1 * c - x2 * s) * outScale);
        }
      }
  } else if (EPI == 2) {
    unsigned short* O = (unsigned short*)out;
#pragma unroll
    for (int mt = 0; mt < 2; ++mt) {
      int m4 = mb + mt * 16 + quad * 4;  // 4 consecutive rows (same b)
      int bb = m4 >> 11;
      int t = m4 & (T_SZ - 1);
#pragma unroll
      for (int nt = 0; nt < 8; ++nt) {
        int n = n0 + nt * 16 + l15;
        int h = n >> 7, d = n & (D_SZ - 1);
        us4 pk;
        pk[0] = f2bf(acc[mt][nt][0]);
        pk[1] = f2bf(acc[mt][nt][1]);
        pk[2] = f2bf(acc[mt][nt][2]);
        pk[3] = f2bf(acc[mt][nt][3]);
        *(us4*)&O[((size_t)((bb * H_SZ + h) * D_SZ + d)) * T_SZ + t] = pk;
      }
    }
  } else {
    float* O = (float*)out;
#pragma unroll
    for (int mt = 0; mt < 2; ++mt)
#pragma unroll
      for (int nt = 0; nt < 8; ++nt)
#pragma unroll
        for (int r = 0; r < 4; ++r) {
          int m = mb + mt * 16 + quad * 4 + r;
          O[(size_t)m * N + n0 + nt * 16 + l15] = acc[mt][nt][r];
        }
  }
}

// Flash attention. Q,K: [B*T][C] bf16 (roped; Q pre-scaled). Vt: [(b*H+h)*D+d][T].
// 64 q-rows per block, 4 waves x 16 rows, kv-tiles of 64.
// All LDS tiles XOR-swizzled at 16B chunks; Q fragments hoisted to registers;
// Ps (P round-trip) is wave-private and aliases the dead Qs buffer -> 48KB LDS, 3 blk/CU.
__global__ __launch_bounds__(256) void attn_fused(const unsigned short* __restrict__ Q,
                                                  const unsigned short* __restrict__ Kg,
                                                  const unsigned short* __restrict__ Vt,
                                                  unsigned short* __restrict__ Y) {
  __shared__ unsigned short Qs[64 * 128];
  __shared__ unsigned short Ks[64 * 128];
  __shared__ unsigned short Vs[128 * 64];   // [d][kv], swizzled
  unsigned short (*Ps)[16 * 64] = reinterpret_cast<unsigned short (*)[16 * 64]>(Qs);
  const int tid = threadIdx.x;
  const int wave = tid >> 6, lane = tid & 63, quad = lane >> 4, l15 = lane & 15;
  const int qt = blockIdx.x, bh = blockIdx.y;
  const int b = bh >> 4, h = bh & 15;
  const float LOG2E = 1.44269504088896f;

  size_t qbase = ((size_t)(b * T_SZ + qt * 64)) * C_SZ + h * D_SZ;
#pragma unroll
  for (int s = 0; s < 4; ++s) {
    int i = s * 256 + tid;
    int row = i >> 4, pos = i & 15, c = pos ^ (row & 15);
    gload16(Q + qbase + (size_t)row * C_SZ + c * 8, (char*)Qs + i * 16);
  }
  __syncthreads();
  bf16x8 aq[4];
#pragma unroll
  for (int ks = 0; ks < 4; ++ks)
    aq[ks] = *(const bf16x8*)&Qs[(wave * 16 + l15) * 128 + (((ks * 4 + quad) ^ l15) * 8)];
  // (all waves finish these reads before any Ps write: two barriers intervene in iter 0)

  float mstate[4], lstate[4];
#pragma unroll
  for (int r = 0; r < 4; ++r) { mstate[r] = -1e30f; lstate[r] = 0.f; }
  f32x4 o[8] = {};

  for (int kt = 0; kt < T_SZ / 64; ++kt) {
    __syncthreads();  // all waves done with prev Ks/Vs
    size_t kbase = ((size_t)(b * T_SZ + kt * 64)) * C_SZ + h * D_SZ;
    size_t vbase = ((size_t)(bh * D_SZ)) * T_SZ + kt * 64;
#pragma unroll
    for (int s = 0; s < 4; ++s) {
      int i = s * 256 + tid;
      int krow = i >> 4, kpos = i & 15, kc = kpos ^ (krow & 15);
      gload16(Kg + kbase + (size_t)krow * C_SZ + kc * 8, (char*)Ks + i * 16);
      int vrow = i >> 3, vpos = i & 7, vc = vpos ^ (vrow & 7);
      gload16(Vt + vbase + (size_t)vrow * T_SZ + vc * 8, (char*)Vs + i * 16);
    }
    __syncthreads();
    // S = Q K^T  (16 q-rows x 64 kv per wave)
    f32x4 sf[4] = {};
#pragma unroll
    for (int nt = 0; nt < 4; ++nt)
#pragma unroll
      for (int ks = 0; ks < 4; ++ks) {
        bf16x8 bk = *(const bf16x8*)&Ks[(nt * 16 + l15) * 128 + (((ks * 4 + quad) ^ l15) * 8)];
        sf[nt] = __builtin_amdgcn_mfma_f32_16x16x32_bf16(aq[ks], bk, sf[nt], 0, 0, 0);
      }
    // online softmax (rows quad*4+r; reduce across the 16 lanes of the quad-group)
    float rmax[4];
#pragma unroll
    for (int r = 0; r < 4; ++r)
      rmax[r] = fmaxf(fmaxf(sf[0][r], sf[1][r]), fmaxf(sf[2][r], sf[3][r]));
#pragma unroll
    for (int off = 8; off >= 1; off >>= 1)
#pragma unroll
      for (int r = 0; r < 4; ++r) rmax[r] = fmaxf(rmax[r], __shfl_xor(rmax[r], off));
    float alpha[4], mnew[4], rsum[4];
#pragma unroll
    for (int r = 0; r < 4; ++r) {
      mnew[r] = fmaxf(mstate[r], rmax[r]);
      alpha[r] = exp2f((mstate[r] - mnew[r]) * LOG2E);
      rsum[r] = 0.f;
    }
#pragma unroll
    for (int nt = 0; nt < 4; ++nt)
#pragma unroll
      for (int r = 0; r < 4; ++r) {
        float p = exp2f((sf[nt][r] - mnew[r]) * LOG2E);
        rsum[r] += p;
        // P[qr][kv], qr=quad*4+r, kv=nt*16+l15; chunk=kv>>3 swizzled by qr&7
        int qr = quad * 4 + r;
        Ps[wave][qr * 64 + (((nt * 2 + (l15 >> 3)) ^ (qr & 7)) * 8) + (l15 & 7)] = f2bf(p);
      }
#pragma unroll
    for (int off = 8; off >= 1; off >>= 1)
#pragma unroll
      for (int r = 0; r < 4; ++r) rsum[r] += __shfl_xor(rsum[r], off);
#pragma unroll
    for (int r = 0; r < 4; ++r) {
      lstate[r] = lstate[r] * alpha[r] + rsum[r];
      mstate[r] = mnew[r];
    }
#pragma unroll
    for (int nt = 0; nt < 8; ++nt)
#pragma unroll
      for (int r = 0; r < 4; ++r) o[nt][r] *= alpha[r];
    // No barrier: Ps[wave] is wave-private; lgkmcnt ordering suffices.
    // O += P V   (P: 16x64 A-layout; V: B-frags from Vs[d][kv])
    bf16x8 ap[2];
#pragma unroll
    for (int ks = 0; ks < 2; ++ks)
      ap[ks] = *(const bf16x8*)&Ps[wave][l15 * 64 + (((ks * 4 + quad) ^ (l15 & 7)) * 8)];
#pragma unroll
    for (int nt = 0; nt < 8; ++nt)
#pragma unroll
      for (int ks = 0; ks < 2; ++ks) {
        bf16x8 bv = *(const bf16x8*)&Vs[(nt * 16 + l15) * 64 + (((ks * 4 + quad) ^ (l15 & 7)) * 8)];
        o[nt] = __builtin_amdgcn_mfma_f32_16x16x32_bf16(ap[ks], bv, o[nt], 0, 0, 0);
      }
  }
#pragma unroll
  for (int nt = 0; nt < 8; ++nt)
#pragma unroll
    for (int r = 0; r < 4; ++r) {
      int m = b * T_SZ + qt * 64 + wave * 16 + quad * 4 + r;
      int col = h * D_SZ + nt * 16 + l15;
      Y[(size_t)m * C_SZ + col] = f2bf(o[nt][r] / lstate[r]);
    }
}

extern "C" void kernel_launch(void* const* d_in, const int* in_sizes, int n_in,
                              void* d_out, int out_size, void* d_ws, size_t ws_size,
                              hipStream_t stream) {
  (void)in_sizes; (void)n_in; (void)out_size; (void)ws_size;
  const float* x    = (const float*)d_in[0];
  const float* cosp = (const float*)d_in[1];
  const float* sinp = (const float*)d_in[2];
  const float* wq   = (const float*)d_in[3];
  const float* wk   = (const float*)d_in[4];
  const float* wv   = (const float*)d_in[5];
  const float* wo   = (const float*)d_in[6];
  float* out = (float*)d_out;

  const size_t XE = (size_t)B_SZ * T_SZ * C_SZ;  // 16,777,216 elements
  const size_t WE = (size_t)C_SZ * C_SZ;         // 4,194,304 elements
  unsigned short* Xb = (unsigned short*)d_ws;    // bf16 x          (33.5 MB)
  unsigned short* Qb = Xb + XE;                  // roped+scaled Q  (33.5 MB)
  unsigned short* Kb = Qb + XE;                  // roped K         (33.5 MB)
  unsigned short* Vt = Kb + XE;                  // V transposed    (33.5 MB)
  unsigned short* Wb = Vt + XE;                  // weight slot     ( 8.4 MB)
  unsigned short* Y  = Xb;                       // alias: Xb dead after V GEMM

  const int M = B_SZ * T_SZ, N = C_SZ, K = C_SZ;
  dim3 ggrid(N / 128, M / 128);
  int nbx = (int)(XE / 4 / 256);
  int nbw = (int)(WE / 4 / 256);
  const float qscale = 0.088388347648318447f;  // 1/sqrt(128)

  cast_f32_bf16<<<nbx, 256, 0, stream>>>(x, Xb, (int)(XE / 4));

  cast_f32_bf16<<<nbw, 256, 0, stream>>>(wq, Wb, (int)(WE / 4));
  gemm_bt<1><<<ggrid, 256, 0, stream>>>(Xb, Wb, Qb, cosp, sinp, qscale, M, N, K);

  cast_f32_bf16<<<nbw, 256, 0, stream>>>(wk, Wb, (int)(WE / 4));
  gemm_bt<1><<<ggrid, 256, 0, stream>>>(Xb, Wb, Kb, cosp, sinp, 1.0f, M, N, K);

  cast_f32_bf16<<<nbw, 256, 0, stream>>>(wv, Wb, (int)(WE / 4));
  gemm_bt<2><<<ggrid, 256, 0, stream>>>(Xb, Wb, Vt, nullptr, nullptr, 1.0f, M, N, K);

  attn_fused<<<dim3(T_SZ / 64, B_SZ * H_SZ), 256, 0, stream>>>(Qb, Kb, Vt, Y);

  cast_f32_bf16<<<nbw, 256, 0, stream>>>(wo, Wb, (int)(WE / 4));
  gemm_bt<3><<<ggrid, 256, 0, stream>>>(Y, Wb, out, nullptr, nullptr, 1.0f, M, N, K);
}

// Round 3
// 871.945 us; speedup vs baseline: 1.4089x; 1.3120x over previous
//
#include <hip/hip_runtime.h>

#define B_SZ 4
#define T_SZ 2048
#define C_SZ 2048
#define H_SZ 16
#define D_SZ 128

typedef __attribute__((ext_vector_type(8))) __bf16 bf16x8;
typedef __attribute__((ext_vector_type(4))) float f32x4;
typedef __attribute__((ext_vector_type(4))) unsigned short us4;

static __device__ __forceinline__ unsigned short f2bf(float f) {
  unsigned u = __builtin_bit_cast(unsigned, f);
  u += 0x7fffu + ((u >> 16) & 1u);
  return (unsigned short)(u >> 16);
}

static __device__ __forceinline__ void gload16(const void* g, void* l) {
  __builtin_amdgcn_global_load_lds((__attribute__((address_space(1))) void*)(g),
                                   (__attribute__((address_space(3))) void*)(l), 16, 0, 0);
}

__global__ __launch_bounds__(256) void cast_f32_bf16(const float* __restrict__ src,
                                                     unsigned short* __restrict__ dst, int n4) {
  int i = blockIdx.x * 256 + threadIdx.x;
  if (i >= n4) return;
  float4 v = ((const float4*)src)[i];
  us4 o;
  o[0] = f2bf(v.x); o[1] = f2bf(v.y); o[2] = f2bf(v.z); o[3] = f2bf(v.w);
  ((us4*)dst)[i] = o;
}

// C[m,n] = sum_k A[m,k]*W[n,k].  A: MxK bf16 row-major, W: NxK bf16 row-major.
// LDS tiles XOR-swizzled at 16B-chunk granularity.
// EPI 1: RoPE epilogue -> bf16; EPI 2: transposed store -> Vt; EPI 3: fp32 store
template <int EPI>
__global__ __launch_bounds__(256) void gemm_bt(const unsigned short* __restrict__ A,
                                               const unsigned short* __restrict__ W,
                                               void* __restrict__ out,
                                               const float* __restrict__ cosp,
                                               const float* __restrict__ sinp,
                                               float outScale, int M, int N, int K) {
  __shared__ unsigned short As[128 * 32];
  __shared__ unsigned short Bs[128 * 32];
  const int tid = threadIdx.x;
  const int wave = tid >> 6, lane = tid & 63, quad = lane >> 4, l15 = lane & 15;
  const int m0 = blockIdx.y * 128, n0 = blockIdx.x * 128;
  f32x4 acc[2][8] = {};
  for (int kt = 0; kt < K; kt += 32) {
    __syncthreads();
#pragma unroll
    for (int s = 0; s < 2; ++s) {
      int i = s * 256 + tid;
      int row = i >> 2, pos = i & 3, c = pos ^ (row & 3);
      gload16(A + (size_t)(m0 + row) * K + kt + c * 8, (char*)As + i * 16);
      gload16(W + (size_t)(n0 + row) * K + kt + c * 8, (char*)Bs + i * 16);
    }
    __syncthreads();
    const int sw = (quad ^ (l15 & 3)) * 8;
    bf16x8 a0 = *(const bf16x8*)&As[(wave * 32 + l15) * 32 + sw];
    bf16x8 a1 = *(const bf16x8*)&As[(wave * 32 + 16 + l15) * 32 + sw];
#pragma unroll
    for (int nt = 0; nt < 8; ++nt) {
      bf16x8 b = *(const bf16x8*)&Bs[(nt * 16 + l15) * 32 + sw];
      acc[0][nt] = __builtin_amdgcn_mfma_f32_16x16x32_bf16(a0, b, acc[0][nt], 0, 0, 0);
      acc[1][nt] = __builtin_amdgcn_mfma_f32_16x16x32_bf16(a1, b, acc[1][nt], 0, 0, 0);
    }
  }
  const int mb = m0 + wave * 32;
  if (EPI == 1) {
    unsigned short* O = (unsigned short*)out;
#pragma unroll
    for (int mt = 0; mt < 2; ++mt)
#pragma unroll
      for (int r = 0; r < 4; ++r) {
        int m = mb + mt * 16 + quad * 4 + r;
        int t = m & (T_SZ - 1);
#pragma unroll
        for (int nt = 0; nt < 4; ++nt) {
          int dd = nt * 16 + l15;
          float c = cosp[t * 64 + dd];
          float s = sinp[t * 64 + dd];
          float x1 = acc[mt][nt][r], x2 = acc[mt][nt + 4][r];
          O[(size_t)m * N + n0 + dd]      = f2bf((x1 * c + x2 * s) * outScale);
          O[(size_t)m * N + n0 + dd + 64] = f2bf((x1 * c - x2 * s) * outScale);
        }
      }
  } else if (EPI == 2) {
    unsigned short* O = (unsigned short*)out;
#pragma unroll
    for (int mt = 0; mt < 2; ++mt) {
      int m4 = mb + mt * 16 + quad * 4;  // 4 consecutive rows (same b)
      int bb = m4 >> 11;
      int t = m4 & (T_SZ - 1);
#pragma unroll
      for (int nt = 0; nt < 8; ++nt) {
        int n = n0 + nt * 16 + l15;
        int h = n >> 7, d = n & (D_SZ - 1);
        us4 pk;
        pk[0] = f2bf(acc[mt][nt][0]);
        pk[1] = f2bf(acc[mt][nt][1]);
        pk[2] = f2bf(acc[mt][nt][2]);
        pk[3] = f2bf(acc[mt][nt][3]);
        *(us4*)&O[((size_t)((bb * H_SZ + h) * D_SZ + d)) * T_SZ + t] = pk;
      }
    }
  } else {
    float* O = (float*)out;
#pragma unroll
    for (int mt = 0; mt < 2; ++mt)
#pragma unroll
      for (int nt = 0; nt < 8; ++nt)
#pragma unroll
        for (int r = 0; r < 4; ++r) {
          int m = mb + mt * 16 + quad * 4 + r;
          O[(size_t)m * N + n0 + nt * 16 + l15] = acc[mt][nt][r];
        }
  }
}

// Flash attention v3. Q,K: [B*T][C] bf16 (roped; Q pre-scaled). Vt: [(b*H+h)*D+d][T].
// Block: 64 q x one (b,h); waves split 2x2: (q-half 32) x (kv-half 32).
// S computed TRANSPOSED (mfma(Kfrag, Qfrag) -> S^T[kv][q]): per-lane-scalar softmax
// stats (q=col=l15), packed P writes, O^T accumulation, vectorized stores.
// K/V double-buffered, ONE barrier per kv-tile; per-wave online softmax over its
// kv-half only, merged once at the end through LDS.
__global__ __launch_bounds__(256, 2) void attn_fused(const unsigned short* __restrict__ Q,
                                                     const unsigned short* __restrict__ Kg,
                                                     const unsigned short* __restrict__ Vt,
                                                     unsigned short* __restrict__ Y) {
  __shared__ unsigned short Ks[2][64 * 128];   // 32 KB (dbuf)
  __shared__ unsigned short Vs[2][128 * 64];   // 32 KB (dbuf), [d][kv]
  __shared__ unsigned short Ps[4][32 * 40];    // 10 KB, per-wave P[q32][kv32], stride 40
  const int tid = threadIdx.x;
  const int wave = tid >> 6, lane = tid & 63, quad = lane >> 4, l15 = lane & 15;
  const int kh = wave & 1, qh = wave >> 1;
  const int qt = blockIdx.x, bh = blockIdx.y;
  const int b = bh >> 4, h = bh & 15;
  const float LOG2E = 1.44269504088896f;

  // Q fragments direct to registers (B-operand: n=q in l15, k contiguous)
  bf16x8 aq[2][4];
  {
    size_t qrow0 = (size_t)(b * T_SZ + qt * 64 + qh * 32);
#pragma unroll
    for (int nt = 0; nt < 2; ++nt)
#pragma unroll
      for (int ks = 0; ks < 4; ++ks)
        aq[nt][ks] = *(const bf16x8*)(Q + (qrow0 + nt * 16 + l15) * C_SZ + h * D_SZ + ks * 32 + quad * 8);
  }

  const size_t kbase0 = ((size_t)(b * T_SZ)) * C_SZ + h * D_SZ;
  const size_t vbase0 = ((size_t)(bh * D_SZ)) * T_SZ;
  // stage tile 0 -> buffer 0
#pragma unroll
  for (int s = 0; s < 4; ++s) {
    int ii = s * 256 + tid;
    int krow = ii >> 4, kpos = ii & 15, kc = kpos ^ (krow & 15);
    gload16(Kg + kbase0 + (size_t)krow * C_SZ + kc * 8, (char*)Ks[0] + ii * 16);
    int vrow = ii >> 3, vpos = ii & 7, vc = vpos ^ (vrow & 7);
    gload16(Vt + vbase0 + (size_t)vrow * T_SZ + vc * 8, (char*)Vs[0] + ii * 16);
  }
  float mstate[2] = {-1e30f, -1e30f}, lstate[2] = {0.f, 0.f};
  f32x4 o[8][2] = {};
  unsigned short* PsW = Ps[wave];
  __syncthreads();   // drains vmcnt: tile 0 + aq ready

  for (int kt = 0; kt < T_SZ / 64; ++kt) {
    const int cur = kt & 1;
    // K,V fragments -> registers (no outstanding loads here: reads are stall-free)
    bf16x8 bk[2][4];
#pragma unroll
    for (int mt = 0; mt < 2; ++mt)
#pragma unroll
      for (int ks = 0; ks < 4; ++ks)
        bk[mt][ks] = *(const bf16x8*)&Ks[cur][(kh * 32 + mt * 16 + l15) * 128 + (((ks * 4 + quad) ^ l15) * 8)];
    bf16x8 bv[8];
#pragma unroll
    for (int dt = 0; dt < 8; ++dt)
      bv[dt] = *(const bf16x8*)&Vs[cur][(dt * 16 + l15) * 64 + (((kh * 4 + quad) ^ (l15 & 7)) * 8)];
    // issue next tile loads; they stay in flight across this iteration's compute,
    // drained by the (compiler-inserted) vmcnt(0) at the end-of-iter barrier
    if (kt + 1 < T_SZ / 64) {
      const int nxt = cur ^ 1;
      size_t kb = kbase0 + (size_t)(kt + 1) * 64 * C_SZ;
      size_t vb = vbase0 + (size_t)(kt + 1) * 64;
#pragma unroll
      for (int s = 0; s < 4; ++s) {
        int ii = s * 256 + tid;
        int krow = ii >> 4, kpos = ii & 15, kc = kpos ^ (krow & 15);
        gload16(Kg + kb + (size_t)krow * C_SZ + kc * 8, (char*)Ks[nxt] + ii * 16);
        int vrow = ii >> 3, vpos = ii & 7, vc = vpos ^ (vrow & 7);
        gload16(Vt + vb + (size_t)vrow * T_SZ + vc * 8, (char*)Vs[nxt] + ii * 16);
      }
    }
    // S^T slice [kv32][q32] = K_slice . Q^T
    f32x4 sf[2][2] = {};
#pragma unroll
    for (int mt = 0; mt < 2; ++mt)
#pragma unroll
      for (int ks = 0; ks < 4; ++ks)
#pragma unroll
        for (int nt = 0; nt < 2; ++nt)
          sf[mt][nt] = __builtin_amdgcn_mfma_f32_16x16x32_bf16(bk[mt][ks], aq[nt][ks], sf[mt][nt], 0, 0, 0);
    // online softmax; q = nt*16 + l15 (per-lane scalar stats), kv rows = mt*16+quad*4+r
    float alpha[2];
#pragma unroll
    for (int nt = 0; nt < 2; ++nt) {
      float rmax = sf[0][nt][0];
#pragma unroll
      for (int mt = 0; mt < 2; ++mt)
#pragma unroll
        for (int r = 0; r < 4; ++r) rmax = fmaxf(rmax, sf[mt][nt][r]);
      rmax = fmaxf(rmax, __shfl_xor(rmax, 16));
      rmax = fmaxf(rmax, __shfl_xor(rmax, 32));
      float mnew = fmaxf(mstate[nt], rmax);
      alpha[nt] = exp2f((mstate[nt] - mnew) * LOG2E);
      float rsum = 0.f;
#pragma unroll
      for (int mt = 0; mt < 2; ++mt) {
        us4 pk;
#pragma unroll
        for (int r = 0; r < 4; ++r) {
          float p = exp2f((sf[mt][nt][r] - mnew) * LOG2E);
          rsum += p;
          pk[r] = f2bf(p);
        }
        *(us4*)&PsW[(nt * 16 + l15) * 40 + mt * 16 + quad * 4] = pk;  // packed b64 write
      }
      rsum += __shfl_xor(rsum, 16);
      rsum += __shfl_xor(rsum, 32);
      lstate[nt] = lstate[nt] * alpha[nt] + rsum;
      mstate[nt] = mnew;
    }
    // rescale O^T
#pragma unroll
    for (int dt = 0; dt < 8; ++dt)
#pragma unroll
      for (int nt = 0; nt < 2; ++nt)
#pragma unroll
        for (int r = 0; r < 4; ++r) o[dt][nt][r] *= alpha[nt];
    // O^T[d][q] += V^T_slice . P^T_slice   (Ps wave-private: lgkm ordering, no barrier)
    bf16x8 ap[2];
#pragma unroll
    for (int nt = 0; nt < 2; ++nt)
      ap[nt] = *(const bf16x8*)&PsW[(nt * 16 + l15) * 40 + quad * 8];
#pragma unroll
    for (int dt = 0; dt < 8; ++dt)
#pragma unroll
      for (int nt = 0; nt < 2; ++nt)
        o[dt][nt] = __builtin_amdgcn_mfma_f32_16x16x32_bf16(bv[dt], ap[nt], o[dt][nt], 0, 0, 0);
    __syncthreads();  // single barrier/iter: compute done + next-tile loads drained
  }

  // merge kv-halves: wave (qh,1) sends (m,l,O^T) to wave (qh,0) via dead K/V buffers
  float* Xch = (float*)Ks;   // 32 KB: [qh][dt*2+nt][lane]
  float* st  = (float*)Vs;   // m[64], l[64]
  if (kh == 1) {
#pragma unroll
    for (int dt = 0; dt < 8; ++dt)
#pragma unroll
      for (int nt = 0; nt < 2; ++nt)
        *(f32x4*)&Xch[((qh * 16 + dt * 2 + nt) * 64 + lane) * 4] = o[dt][nt];
    if (quad == 0) {
#pragma unroll
      for (int nt = 0; nt < 2; ++nt) {
        int q = qh * 32 + nt * 16 + l15;
        st[q] = mstate[nt];
        st[64 + q] = lstate[nt];
      }
    }
  }
  __syncthreads();
  if (kh == 0) {
#pragma unroll
    for (int nt = 0; nt < 2; ++nt) {
      int q = qh * 32 + nt * 16 + l15;
      float m1 = st[q], l1 = st[64 + q];
      float M = fmaxf(mstate[nt], m1);
      float a0 = exp2f((mstate[nt] - M) * LOG2E);
      float a1 = exp2f((m1 - M) * LOG2E);
      float L = lstate[nt] * a0 + l1 * a1;
      float inv = 1.0f / L;
      size_t row = (size_t)(b * T_SZ + qt * 64) + q;
#pragma unroll
      for (int dt = 0; dt < 8; ++dt) {
        f32x4 o1 = *(const f32x4*)&Xch[((qh * 16 + dt * 2 + nt) * 64 + lane) * 4];
        us4 pk;
#pragma unroll
        for (int r = 0; r < 4; ++r)
          pk[r] = f2bf((o[dt][nt][r] * a0 + o1[r] * a1) * inv);
        *(us4*)&Y[row * C_SZ + h * D_SZ + dt * 16 + quad * 4] = pk;
      }
    }
  }
}

extern "C" void kernel_launch(void* const* d_in, const int* in_sizes, int n_in,
                              void* d_out, int out_size, void* d_ws, size_t ws_size,
                              hipStream_t stream) {
  (void)in_sizes; (void)n_in; (void)out_size; (void)ws_size;
  const float* x    = (const float*)d_in[0];
  const float* cosp = (const float*)d_in[1];
  const float* sinp = (const float*)d_in[2];
  const float* wq   = (const float*)d_in[3];
  const float* wk   = (const float*)d_in[4];
  const float* wv   = (const float*)d_in[5];
  const float* wo   = (const float*)d_in[6];
  float* out = (float*)d_out;

  const size_t XE = (size_t)B_SZ * T_SZ * C_SZ;  // 16,777,216 elements
  const size_t WE = (size_t)C_SZ * C_SZ;         // 4,194,304 elements
  unsigned short* Xb = (unsigned short*)d_ws;    // bf16 x          (33.5 MB)
  unsigned short* Qb = Xb + XE;                  // roped+scaled Q  (33.5 MB)
  unsigned short* Kb = Qb + XE;                  // roped K         (33.5 MB)
  unsigned short* Vt = Kb + XE;                  // V transposed    (33.5 MB)
  unsigned short* Wb = Vt + XE;                  // weight slot     ( 8.4 MB)
  unsigned short* Y  = Xb;                       // alias: Xb dead after V GEMM

  const int M = B_SZ * T_SZ, N = C_SZ, K = C_SZ;
  dim3 ggrid(N / 128, M / 128);
  int nbx = (int)(XE / 4 / 256);
  int nbw = (int)(WE / 4 / 256);
  const float qscale = 0.088388347648318447f;  // 1/sqrt(128)

  cast_f32_bf16<<<nbx, 256, 0, stream>>>(x, Xb, (int)(XE / 4));

  cast_f32_bf16<<<nbw, 256, 0, stream>>>(wq, Wb, (int)(WE / 4));
  gemm_bt<1><<<ggrid, 256, 0, stream>>>(Xb, Wb, Qb, cosp, sinp, qscale, M, N, K);

  cast_f32_bf16<<<nbw, 256, 0, stream>>>(wk, Wb, (int)(WE / 4));
  gemm_bt<1><<<ggrid, 256, 0, stream>>>(Xb, Wb, Kb, cosp, sinp, 1.0f, M, N, K);

  cast_f32_bf16<<<nbw, 256, 0, stream>>>(wv, Wb, (int)(WE / 4));
  gemm_bt<2><<<ggrid, 256, 0, stream>>>(Xb, Wb, Vt, nullptr, nullptr, 1.0f, M, N, K);

  attn_fused<<<dim3(T_SZ / 64, B_SZ * H_SZ), 256, 0, stream>>>(Qb, Kb, Vt, Y);

  cast_f32_bf16<<<nbw, 256, 0, stream>>>(wo, Wb, (int)(WE / 4));
  gemm_bt<3><<<ggrid, 256, 0, stream>>>(Y, Wb, out, nullptr, nullptr, 1.0f, M, N, K);
}

// Round 6
// 850.190 us; speedup vs baseline: 1.4449x; 1.0256x over previous
//
#include <hip/hip_runtime.h>

#define B_SZ 4
#define T_SZ 2048
#define C_SZ 2048
#define H_SZ 16
#define D_SZ 128

typedef __attribute__((ext_vector_type(8))) __bf16 bf16x8;
typedef __attribute__((ext_vector_type(4))) float f32x4;
typedef __attribute__((ext_vector_type(4))) unsigned short us4;

static __device__ __forceinline__ unsigned short f2bf(float f) {  // RNE everywhere
  unsigned u = __builtin_bit_cast(unsigned, f);
  u += 0x7fffu + ((u >> 16) & 1u);
  return (unsigned short)(u >> 16);
}

static __device__ __forceinline__ void gload16(const void* g, void* l) {
  __builtin_amdgcn_global_load_lds((__attribute__((address_space(1))) void*)(g),
                                   (__attribute__((address_space(3))) void*)(l), 16, 0, 0);
}

__global__ __launch_bounds__(256) void cast_f32_bf16(const float* __restrict__ src,
                                                     unsigned short* __restrict__ dst, int n4) {
  int i = blockIdx.x * 256 + threadIdx.x;
  if (i >= n4) return;
  float4 v = ((const float4*)src)[i];
  us4 o;
  o[0] = f2bf(v.x); o[1] = f2bf(v.y); o[2] = f2bf(v.z); o[3] = f2bf(v.w);
  ((us4*)dst)[i] = o;
}

// C[m,n] = sum_k A[m,k]*W[n,k].  A: MxK bf16 row-major, W: NxK bf16 row-major.
// LDS tiles XOR-swizzled at 16B-chunk granularity.
// EPI 1: RoPE epilogue -> bf16; EPI 2: transposed store -> Vt; EPI 3: fp32 store
template <int EPI>
__global__ __launch_bounds__(256) void gemm_bt(const unsigned short* __restrict__ A,
                                               const unsigned short* __restrict__ W,
                                               void* __restrict__ out,
                                               const float* __restrict__ cosp,
                                               const float* __restrict__ sinp,
                                               float outScale, int M, int N, int K) {
  __shared__ unsigned short As[128 * 32];
  __shared__ unsigned short Bs[128 * 32];
  const int tid = threadIdx.x;
  const int wave = tid >> 6, lane = tid & 63, quad = lane >> 4, l15 = lane & 15;
  const int m0 = blockIdx.y * 128, n0 = blockIdx.x * 128;
  f32x4 acc[2][8] = {};
  for (int kt = 0; kt < K; kt += 32) {
    __syncthreads();
#pragma unroll
    for (int s = 0; s < 2; ++s) {
      int i = s * 256 + tid;
      int row = i >> 2, pos = i & 3, c = pos ^ (row & 3);
      gload16(A + (size_t)(m0 + row) * K + kt + c * 8, (char*)As + i * 16);
      gload16(W + (size_t)(n0 + row) * K + kt + c * 8, (char*)Bs + i * 16);
    }
    __syncthreads();
    const int sw = (quad ^ (l15 & 3)) * 8;
    bf16x8 a0 = *(const bf16x8*)&As[(wave * 32 + l15) * 32 + sw];
    bf16x8 a1 = *(const bf16x8*)&As[(wave * 32 + 16 + l15) * 32 + sw];
#pragma unroll
    for (int nt = 0; nt < 8; ++nt) {
      bf16x8 b = *(const bf16x8*)&Bs[(nt * 16 + l15) * 32 + sw];
      acc[0][nt] = __builtin_amdgcn_mfma_f32_16x16x32_bf16(a0, b, acc[0][nt], 0, 0, 0);
      acc[1][nt] = __builtin_amdgcn_mfma_f32_16x16x32_bf16(a1, b, acc[1][nt], 0, 0, 0);
    }
  }
  const int mb = m0 + wave * 32;
  if (EPI == 1) {
    unsigned short* O = (unsigned short*)out;
#pragma unroll
    for (int mt = 0; mt < 2; ++mt)
#pragma unroll
      for (int r = 0; r < 4; ++r) {
        int m = mb + mt * 16 + quad * 4 + r;
        int t = m & (T_SZ - 1);
#pragma unroll
        for (int nt = 0; nt < 4; ++nt) {
          int dd = nt * 16 + l15;
          float c = cosp[t * 64 + dd];
          float s = sinp[t * 64 + dd];
          float x1 = acc[mt][nt][r], x2 = acc[mt][nt + 4][r];
          O[(size_t)m * N + n0 + dd]      = f2bf((x1 * c + x2 * s) * outScale);
          O[(size_t)m * N + n0 + dd + 64] = f2bf((x1 * c - x2 * s) * outScale);
        }
      }
  } else if (EPI == 2) {
    unsigned short* O = (unsigned short*)out;
#pragma unroll
    for (int mt = 0; mt < 2; ++mt) {
      int m4 = mb + mt * 16 + quad * 4;  // 4 consecutive rows (same b)
      int bb = m4 >> 11;
      int t = m4 & (T_SZ - 1);
#pragma unroll
      for (int nt = 0; nt < 8; ++nt) {
        int n = n0 + nt * 16 + l15;
        int h = n >> 7, d = n & (D_SZ - 1);
        us4 pk;
        pk[0] = f2bf(acc[mt][nt][0]);
        pk[1] = f2bf(acc[mt][nt][1]);
        pk[2] = f2bf(acc[mt][nt][2]);
        pk[3] = f2bf(acc[mt][nt][3]);
        *(us4*)&O[((size_t)((bb * H_SZ + h) * D_SZ + d)) * T_SZ + t] = pk;
      }
    }
  } else {
    float* O = (float*)out;
#pragma unroll
    for (int mt = 0; mt < 2; ++mt)
#pragma unroll
      for (int nt = 0; nt < 8; ++nt)
#pragma unroll
        for (int r = 0; r < 4; ++r) {
          int m = mb + mt * 16 + quad * 4 + r;
          O[(size_t)m * N + n0 + nt * 16 + l15] = acc[mt][nt][r];
        }
  }
}

static __device__ __forceinline__ void stage_kv(const unsigned short* __restrict__ Kg,
                                                const unsigned short* __restrict__ Vt,
                                                unsigned short* Kbuf, unsigned short* Vbuf,
                                                size_t kbase0, size_t vbase0, int kt, int tid) {
  size_t kb = kbase0 + (size_t)kt * 64 * C_SZ;
  size_t vb = vbase0 + (size_t)kt * 64;
#pragma unroll
  for (int s = 0; s < 4; ++s) {
    int ii = s * 256 + tid;
    int krow = ii >> 4, kpos = ii & 15, kc = kpos ^ (krow & 15);
    gload16(Kg + kb + (size_t)krow * C_SZ + kc * 8, (char*)Kbuf + ii * 16);
    int vrow = ii >> 3, vpos = ii & 7, vc = vpos ^ (vrow & 7);
    gload16(Vt + vb + (size_t)vrow * T_SZ + vc * 8, (char*)Vbuf + ii * 16);
  }
}

// Flash attention v6 = v5 structure with R3's verified numerics restored:
// RNE (f2bf) on all P and Y packing; softmax in e-base with fp32 LOG2E mul
// (Q pre-scaled by 1/sqrt(d) only). Waves 2x2 (q-half x kv-half); S transposed;
// K/V double-buffered; paired kv-tiles; Ps wave-private slot reuse + compiler fence.
__global__ __launch_bounds__(256, 2) void attn_fused(const unsigned short* __restrict__ Q,
                                                     const unsigned short* __restrict__ Kg,
                                                     const unsigned short* __restrict__ Vt,
                                                     unsigned short* __restrict__ Y) {
  __shared__ unsigned short Ks[2][64 * 128];   // 32 KB (dbuf)
  __shared__ unsigned short Vs[2][128 * 64];   // 32 KB (dbuf), [d][kv]
  __shared__ unsigned short Ps[4][32 * 40];    // 10 KB, per-wave P[q32][kv32]
  const int tid = threadIdx.x;
  const int wave = tid >> 6, lane = tid & 63, quad = lane >> 4, l15 = lane & 15;
  const int kh = wave & 1, qh = wave >> 1;
  const int qt = blockIdx.x, bh = blockIdx.y;
  const int b = bh >> 4, h = bh & 15;
  const float LOG2E = 1.44269504088896f;

  // Q fragments direct to registers (B-operand: n=q in l15, k contiguous)
  bf16x8 aq[2][4];
  {
    size_t qrow0 = (size_t)(b * T_SZ + qt * 64 + qh * 32);
#pragma unroll
    for (int nt = 0; nt < 2; ++nt)
#pragma unroll
      for (int ks = 0; ks < 4; ++ks)
        aq[nt][ks] = *(const bf16x8*)(Q + (qrow0 + nt * 16 + l15) * C_SZ + h * D_SZ + ks * 32 + quad * 8);
  }

  const size_t kbase0 = ((size_t)(b * T_SZ)) * C_SZ + h * D_SZ;
  const size_t vbase0 = ((size_t)(bh * D_SZ)) * T_SZ;
  stage_kv(Kg, Vt, Ks[0], Vs[0], kbase0, vbase0, 0, tid);
  stage_kv(Kg, Vt, Ks[1], Vs[1], kbase0, vbase0, 1, tid);

  float mstate[2] = {-1e30f, -1e30f}, lstate[2] = {0.f, 0.f};
  f32x4 o[8][2] = {};
  unsigned short* PsW = Ps[wave];
  __syncthreads();   // tiles 0,1 staged (vmcnt drained); aq ready

  for (int jt = 0; jt < T_SZ / 128; ++jt) {
    // ---- tile A (buf0): frags -> regs, S_A
    bf16x8 bkA[2][4], bvA[8];
#pragma unroll
    for (int mt = 0; mt < 2; ++mt)
#pragma unroll
      for (int ks = 0; ks < 4; ++ks)
        bkA[mt][ks] = *(const bf16x8*)&Ks[0][(kh * 32 + mt * 16 + l15) * 128 + (((ks * 4 + quad) ^ l15) * 8)];
#pragma unroll
    for (int dt = 0; dt < 8; ++dt)
      bvA[dt] = *(const bf16x8*)&Vs[0][(dt * 16 + l15) * 64 + (((kh * 4 + quad) ^ (l15 & 7)) * 8)];
    f32x4 sfA[2][2] = {};
#pragma unroll
    for (int mt = 0; mt < 2; ++mt)
#pragma unroll
      for (int ks = 0; ks < 4; ++ks)
#pragma unroll
        for (int nt = 0; nt < 2; ++nt)
          sfA[mt][nt] = __builtin_amdgcn_mfma_f32_16x16x32_bf16(bkA[mt][ks], aq[nt][ks], sfA[mt][nt], 0, 0, 0);
    __syncthreads();                       // buf0 consumed by all waves
    if (jt + 1 < T_SZ / 128) stage_kv(Kg, Vt, Ks[0], Vs[0], kbase0, vbase0, 2 * jt + 2, tid);
    // ---- tile B (buf1): frags -> regs, S_B
    bf16x8 bkB[2][4], bvB[8];
#pragma unroll
    for (int mt = 0; mt < 2; ++mt)
#pragma unroll
      for (int ks = 0; ks < 4; ++ks)
        bkB[mt][ks] = *(const bf16x8*)&Ks[1][(kh * 32 + mt * 16 + l15) * 128 + (((ks * 4 + quad) ^ l15) * 8)];
#pragma unroll
    for (int dt = 0; dt < 8; ++dt)
      bvB[dt] = *(const bf16x8*)&Vs[1][(dt * 16 + l15) * 64 + (((kh * 4 + quad) ^ (l15 & 7)) * 8)];
    f32x4 sfB[2][2] = {};
#pragma unroll
    for (int mt = 0; mt < 2; ++mt)
#pragma unroll
      for (int ks = 0; ks < 4; ++ks)
#pragma unroll
        for (int nt = 0; nt < 2; ++nt)
          sfB[mt][nt] = __builtin_amdgcn_mfma_f32_16x16x32_bf16(bkB[mt][ks], aq[nt][ks], sfB[mt][nt], 0, 0, 0);
    // ---- paired online softmax (e-base, fp32 LOG2E; q = nt*16+l15 per-lane scalar)
    float alpha[2], rsum[2];
#pragma unroll
    for (int nt = 0; nt < 2; ++nt) {
      float rmax = sfA[0][nt][0];
#pragma unroll
      for (int mt = 0; mt < 2; ++mt)
#pragma unroll
        for (int r = 0; r < 4; ++r) {
          rmax = fmaxf(rmax, sfA[mt][nt][r]);
          rmax = fmaxf(rmax, sfB[mt][nt][r]);
        }
      rmax = fmaxf(rmax, __shfl_xor(rmax, 16));
      rmax = fmaxf(rmax, __shfl_xor(rmax, 32));
      float mnew = fmaxf(mstate[nt], rmax);
      alpha[nt] = exp2f((mstate[nt] - mnew) * LOG2E);
      mstate[nt] = mnew;
      rsum[nt] = 0.f;
    }
    // one O-rescale per 128 kv
#pragma unroll
    for (int dt = 0; dt < 8; ++dt)
#pragma unroll
      for (int nt = 0; nt < 2; ++nt)
        o[dt][nt] *= alpha[nt];
    // P_A -> Ps (RNE), PV_A
#pragma unroll
    for (int nt = 0; nt < 2; ++nt)
#pragma unroll
      for (int mt = 0; mt < 2; ++mt) {
        us4 pk;
        float p0 = exp2f((sfA[mt][nt][0] - mstate[nt]) * LOG2E);
        float p1 = exp2f((sfA[mt][nt][1] - mstate[nt]) * LOG2E);
        float p2 = exp2f((sfA[mt][nt][2] - mstate[nt]) * LOG2E);
        float p3 = exp2f((sfA[mt][nt][3] - mstate[nt]) * LOG2E);
        rsum[nt] += (p0 + p1) + (p2 + p3);
        pk[0] = f2bf(p0); pk[1] = f2bf(p1); pk[2] = f2bf(p2); pk[3] = f2bf(p3);
        *(us4*)&PsW[(nt * 16 + l15) * 40 + mt * 16 + quad * 4] = pk;
      }
    {
      bf16x8 ap[2];
#pragma unroll
      for (int nt = 0; nt < 2; ++nt)
        ap[nt] = *(const bf16x8*)&PsW[(nt * 16 + l15) * 40 + quad * 8];
#pragma unroll
      for (int dt = 0; dt < 8; ++dt)
#pragma unroll
        for (int nt = 0; nt < 2; ++nt)
          o[dt][nt] = __builtin_amdgcn_mfma_f32_16x16x32_bf16(bvA[dt], ap[nt], o[dt][nt], 0, 0, 0);
    }
    // compiler-level fence: Ps slot reused for P_B; forbid hoisting B writes above A reads
    asm volatile("" ::: "memory");
    // P_B -> same Ps slot (RNE), PV_B
#pragma unroll
    for (int nt = 0; nt < 2; ++nt)
#pragma unroll
      for (int mt = 0; mt < 2; ++mt) {
        us4 pk;
        float p0 = exp2f((sfB[mt][nt][0] - mstate[nt]) * LOG2E);
        float p1 = exp2f((sfB[mt][nt][1] - mstate[nt]) * LOG2E);
        float p2 = exp2f((sfB[mt][nt][2] - mstate[nt]) * LOG2E);
        float p3 = exp2f((sfB[mt][nt][3] - mstate[nt]) * LOG2E);
        rsum[nt] += (p0 + p1) + (p2 + p3);
        pk[0] = f2bf(p0); pk[1] = f2bf(p1); pk[2] = f2bf(p2); pk[3] = f2bf(p3);
        *(us4*)&PsW[(nt * 16 + l15) * 40 + mt * 16 + quad * 4] = pk;
      }
    {
      bf16x8 ap[2];
#pragma unroll
      for (int nt = 0; nt < 2; ++nt)
        ap[nt] = *(const bf16x8*)&PsW[(nt * 16 + l15) * 40 + quad * 8];
#pragma unroll
      for (int dt = 0; dt < 8; ++dt)
#pragma unroll
        for (int nt = 0; nt < 2; ++nt)
          o[dt][nt] = __builtin_amdgcn_mfma_f32_16x16x32_bf16(bvB[dt], ap[nt], o[dt][nt], 0, 0, 0);
    }
#pragma unroll
    for (int nt = 0; nt < 2; ++nt) {
      rsum[nt] += __shfl_xor(rsum[nt], 16);
      rsum[nt] += __shfl_xor(rsum[nt], 32);
      lstate[nt] = lstate[nt] * alpha[nt] + rsum[nt];
    }
    __syncthreads();                       // buf1 consumed by all waves
    if (jt + 1 < T_SZ / 128) stage_kv(Kg, Vt, Ks[1], Vs[1], kbase0, vbase0, 2 * jt + 3, tid);
  }

  // merge kv-halves: wave (qh,1) sends (m,l,O^T) to wave (qh,0) via dead K/V buffers
  float* Xch = (float*)Ks;   // 32 KB: [qh][dt*2+nt][lane]
  float* st  = (float*)Vs;   // m[64], l[64]
  if (kh == 1) {
#pragma unroll
    for (int dt = 0; dt < 8; ++dt)
#pragma unroll
      for (int nt = 0; nt < 2; ++nt)
        *(f32x4*)&Xch[((qh * 16 + dt * 2 + nt) * 64 + lane) * 4] = o[dt][nt];
    if (quad == 0) {
#pragma unroll
      for (int nt = 0; nt < 2; ++nt) {
        int q = qh * 32 + nt * 16 + l15;
        st[q] = mstate[nt];
        st[64 + q] = lstate[nt];
      }
    }
  }
  __syncthreads();
  if (kh == 0) {
#pragma unroll
    for (int nt = 0; nt < 2; ++nt) {
      int q = qh * 32 + nt * 16 + l15;
      float m1 = st[q], l1 = st[64 + q];
      float M = fmaxf(mstate[nt], m1);
      float a0 = exp2f((mstate[nt] - M) * LOG2E);
      float a1 = exp2f((m1 - M) * LOG2E);
      float L = lstate[nt] * a0 + l1 * a1;
      float inv = 1.0f / L;
      size_t row = (size_t)(b * T_SZ + qt * 64) + q;
#pragma unroll
      for (int dt = 0; dt < 8; ++dt) {
        f32x4 o1 = *(const f32x4*)&Xch[((qh * 16 + dt * 2 + nt) * 64 + lane) * 4];
        us4 pk;
        pk[0] = f2bf((o[dt][nt][0] * a0 + o1[0] * a1) * inv);
        pk[1] = f2bf((o[dt][nt][1] * a0 + o1[1] * a1) * inv);
        pk[2] = f2bf((o[dt][nt][2] * a0 + o1[2] * a1) * inv);
        pk[3] = f2bf((o[dt][nt][3] * a0 + o1[3] * a1) * inv);
        *(us4*)&Y[row * C_SZ + h * D_SZ + dt * 16 + quad * 4] = pk;
      }
    }
  }
}

extern "C" void kernel_launch(void* const* d_in, const int* in_sizes, int n_in,
                              void* d_out, int out_size, void* d_ws, size_t ws_size,
                              hipStream_t stream) {
  (void)in_sizes; (void)n_in; (void)out_size; (void)ws_size;
  const float* x    = (const float*)d_in[0];
  const float* cosp = (const float*)d_in[1];
  const float* sinp = (const float*)d_in[2];
  const float* wq   = (const float*)d_in[3];
  const float* wk   = (const float*)d_in[4];
  const float* wv   = (const float*)d_in[5];
  const float* wo   = (const float*)d_in[6];
  float* out = (float*)d_out;

  const size_t XE = (size_t)B_SZ * T_SZ * C_SZ;  // 16,777,216 elements
  const size_t WE = (size_t)C_SZ * C_SZ;         // 4,194,304 elements
  unsigned short* Xb = (unsigned short*)d_ws;    // bf16 x          (33.5 MB)
  unsigned short* Qb = Xb + XE;                  // roped+scaled Q  (33.5 MB)
  unsigned short* Kb = Qb + XE;                  // roped K         (33.5 MB)
  unsigned short* Vt = Kb + XE;                  // V transposed    (33.5 MB)
  unsigned short* Wb = Vt + XE;                  // weight slot     ( 8.4 MB)
  unsigned short* Y  = Xb;                       // alias: Xb dead after V GEMM

  const int M = B_SZ * T_SZ, N = C_SZ, K = C_SZ;
  dim3 ggrid(N / 128, M / 128);
  int nbx = (int)(XE / 4 / 256);
  int nbw = (int)(WE / 4 / 256);
  const float qscale = 0.088388347648318447f;  // 1/sqrt(128)  (R3 numerics)

  cast_f32_bf16<<<nbx, 256, 0, stream>>>(x, Xb, (int)(XE / 4));

  cast_f32_bf16<<<nbw, 256, 0, stream>>>(wq, Wb, (int)(WE / 4));
  gemm_bt<1><<<ggrid, 256, 0, stream>>>(Xb, Wb, Qb, cosp, sinp, qscale, M, N, K);

  cast_f32_bf16<<<nbw, 256, 0, stream>>>(wk, Wb, (int)(WE / 4));
  gemm_bt<1><<<ggrid, 256, 0, stream>>>(Xb, Wb, Kb, cosp, sinp, 1.0f, M, N, K);

  cast_f32_bf16<<<nbw, 256, 0, stream>>>(wv, Wb, (int)(WE / 4));
  gemm_bt<2><<<ggrid, 256, 0, stream>>>(Xb, Wb, Vt, nullptr, nullptr, 1.0f, M, N, K);

  attn_fused<<<dim3(T_SZ / 64, B_SZ * H_SZ), 256, 0, stream>>>(Qb, Kb, Vt, Y);

  cast_f32_bf16<<<nbw, 256, 0, stream>>>(wo, Wb, (int)(WE / 4));
  gemm_bt<3><<<ggrid, 256, 0, stream>>>(Y, Wb, out, nullptr, nullptr, 1.0f, M, N, K);
}